// Round 24
// baseline (268.939 us; speedup 1.0000x reference)
//
#include <hip/hip_runtime.h>

#define N_NODES 50000
#define N_EDGES 800000
#define F 64
#define EDIM 16
#define NEG_SLOPE 0.01f
#define G 128                                // edges per staged group
#define EPB 256                              // edges per block (2 groups)
#define NBLK_E (N_EDGES / EPB)               // 3125 (exact)
#define WSLOT_EA 66                          // (32+1 pad) slots * 2 uint4
#define WSLOT_P  34                          // 32 + 2 pad slots
#define NPB 32                               // nodes per block (node kernel)
#define NBLK ((N_NODES + NPB - 1) / NPB)     // 1563
#define NPW 8                                // nodes per wave (node kernel)
#define CPAD 16                              // counter stride: 1 per 64B line
#define SCAN_B 1024
#define SCAN_NB ((N_NODES + SCAN_B - 1) / SCAN_B)   // 49

typedef _Float16 half2_t __attribute__((ext_vector_type(2)));

__device__ __forceinline__ float dot2u(unsigned u, half2_t w, float acc) {
    return __builtin_amdgcn_fdot2(__builtin_bit_cast(half2_t, u), w, acc, false);
}

// ---------------- CSR build ----------------
__global__ __launch_bounds__(256) void hist_kernel(const int* __restrict__ ei,
                                                   int* __restrict__ count,
                                                   int* __restrict__ rank) {
    int e = blockIdx.x * blockDim.x + threadIdx.x;
    if (e < N_EDGES)
        rank[e] = atomicAdd(&count[ei[N_EDGES + e] * CPAD], 1);
}

__global__ __launch_bounds__(SCAN_B) void scan_partial_kernel(const int* __restrict__ count,
                                                              int* __restrict__ rowptr,
                                                              int* __restrict__ blockSum) {
    __shared__ int buf[SCAN_B];
    const int b = blockIdx.x, tid = threadIdx.x;
    const int i = b * SCAN_B + tid;
    int v = (i < N_NODES) ? count[i * CPAD] : 0;
    buf[tid] = v;
    __syncthreads();
    for (int off = 1; off < SCAN_B; off <<= 1) {
        int t = (tid >= off) ? buf[tid - off] : 0;
        __syncthreads();
        buf[tid] += t;
        __syncthreads();
    }
    if (i < N_NODES) rowptr[i] = buf[tid] - v;      // exclusive within block
    if (tid == SCAN_B - 1) blockSum[b] = buf[tid];
}

__global__ void scan_tops_kernel(int* __restrict__ blockSum) {
    const int lane = threadIdx.x;                    // 64 threads = 1 wave
    int v = (lane < SCAN_NB) ? blockSum[lane] : 0;
    int s = v;
    for (int off = 1; off < 64; off <<= 1) {
        int t = __shfl_up(s, off);
        if (lane >= off) s += t;
    }
    if (lane < SCAN_NB) blockSum[lane] = s - v;      // exclusive block offsets
}

// atomic-free placement: pos = rowptr[d] + blockSum[d/1024] + rank[e]
__global__ __launch_bounds__(256) void place_kernel(const int* __restrict__ ei,
                                                    const int* __restrict__ rowptr,
                                                    const int* __restrict__ blockSum,
                                                    const int* __restrict__ rank,
                                                    int2* __restrict__ pairsSD,
                                                    int* __restrict__ eid) {
    int e = blockIdx.x * blockDim.x + threadIdx.x;
    if (e < N_EDGES) {
        int s = ei[e];
        int d = ei[N_EDGES + e];
        int pos = rowptr[d] + blockSum[d >> 10] + rank[e];
        pairsSD[pos] = make_int2(s, d);
        eid[pos] = e;
    }
}

// gather-permute + fp32->fp16 convert: eaPh[j] = (half)ea[eid[j]].
__global__ __launch_bounds__(256) void permute_kernel(const float4* __restrict__ ea4,
                                                      const int* __restrict__ eid,
                                                      uint4* __restrict__ eaPh) {
    int t = blockIdx.x * blockDim.x + threadIdx.x;
    if (t < N_EDGES * 2) {
        int j = t >> 1, c = t & 1;
        size_t r = (size_t)eid[j];
        float4 a = ea4[(r << 2) + (c << 1)];
        float4 b = ea4[(r << 2) + (c << 1) + 1];
        half2_t h0, h1, h2, h3;
        h0[0] = (_Float16)a.x; h0[1] = (_Float16)a.y;
        h1[0] = (_Float16)a.z; h1[1] = (_Float16)a.w;
        h2[0] = (_Float16)b.x; h2[1] = (_Float16)b.y;
        h3[0] = (_Float16)b.z; h3[1] = (_Float16)b.w;
        uint4 o;
        o.x = __builtin_bit_cast(unsigned, h0);
        o.y = __builtin_bit_cast(unsigned, h1);
        o.z = __builtin_bit_cast(unsigned, h2);
        o.w = __builtin_bit_cast(unsigned, h3);
        eaPh[t] = o;
    }
}

// fp32 -> fp16 convert for x (node features), float4 -> 4 halves per thread
__global__ __launch_bounds__(256) void tofp16_kernel(const float4* __restrict__ src4,
                                                     uint2* __restrict__ dst2) {
    int t = blockIdx.x * blockDim.x + threadIdx.x;
    if (t < N_NODES * F / 4) {
        float4 v = src4[t];
        half2_t a, b;
        a[0] = (_Float16)v.x; a[1] = (_Float16)v.y;
        b[0] = (_Float16)v.z; b[1] = (_Float16)v.w;
        uint2 o;
        o.x = __builtin_bit_cast(unsigned, a);
        o.y = __builtin_bit_cast(unsigned, b);
        dst2[t] = o;
    }
}

// ---------------- fuse readout weights ----------------
__global__ void fuse_weights_kernel(
    const float* __restrict__ W1, const float* __restrict__ b1,
    const float* __restrict__ W2, const float* __restrict__ b2,
    float* __restrict__ Wf, float* __restrict__ bf) {
    const int t = threadIdx.x;     // 128 threads
    const int i = t >> 1;
    const int j = t & 1;
    float acc = 0.f;
    for (int k = 0; k < 128; ++k) acc += W1[i * 128 + k] * W2[k * 2 + j];
    Wf[i * 2 + j] = acc;
    if (i == 0) {
        float accb = b2[j];
        for (int k = 0; k < 128; ++k) accb += b1[k] * W2[k * 2 + j];
        bf[j] = accb;
    }
}

// ---------------- edge kernel: fp16 h gather (128B rows, L2-resident working set) ----------------
__global__ __launch_bounds__(256) void edge_kernel(
    const _Float16* __restrict__ h16,    // [N][64] fp16 node features
    const int2* __restrict__ pairsSD,
    const uint4* __restrict__ eaPh,      // [E][2] uint4 = 16 halfs per edge
    const float* __restrict__ We, const float* __restrict__ be,
    float* __restrict__ aggr)
{
    __shared__ uint4 eaS[2][4 * WSLOT_EA];   // 8448 B
    __shared__ int2  pairsS[2][4 * WSLOT_P]; // 2176 B
    const int tid  = threadIdx.x;
    const int lane = tid & 63;
    const int wid  = tid >> 6;           // 0..3
    const int base = wid * 32;

    const int eBeg = blockIdx.x * EPB;   // all blocks exactly EPB edges
    const int ngroups = EPB / G;         // 2

    half2_t weh[8];
#pragma unroll
    for (int k = 0; k < 8; ++k) {
        half2_t w;
        w[0] = (_Float16)We[(2 * k + 0) * F + lane];
        w[1] = (_Float16)We[(2 * k + 1) * F + lane];
        weh[k] = w;
    }
    const float beR = be[lane];

    // ---- stage group 0 (main + pads) straight into LDS buffer 0 ----
    {
        const int j = tid >> 1, c = tid & 1;
        eaS[0][(j >> 5) * WSLOT_EA + (j & 31) * 2 + c] =
            eaPh[(size_t)eBeg * 2 + tid];
        ((int*)pairsS[0])[((j >> 5) * WSLOT_P + (j & 31)) * 2 + c] =
            ((const int*)(pairsSD + eBeg))[tid];
        if (tid < 8) {   // ea pads: wave w slot 32 = group 1's edge (base)
            const int w = tid >> 1, cc = tid & 1;
            const int src = min(eBeg + G + w * 32, N_EDGES - 1);
            eaS[0][w * WSLOT_EA + 64 + cc] = eaPh[(size_t)src * 2 + cc];
        }
        if (tid < 16) {  // pairs pads: wave w slots 32,33 = group 1's first 2 pairs
            const int w = tid >> 2, sl = (tid >> 1) & 1, ic = tid & 1;
            const int src = min(eBeg + G + w * 32 + sl, N_EDGES - 1);
            ((int*)pairsS[0])[(w * WSLOT_P + 32 + sl) * 2 + ic] =
                ((const int*)pairsSD)[src * 2 + ic];
        }
    }
    // prime pipeline registers from global (overlaps the staging above)
    int2 sdA = pairsSD[eBeg + base];
    int2 sdB = pairsSD[eBeg + base + 1];
    float hsA = (float)h16[(((unsigned)sdA.x) << 6) + lane];
    uint4 qA0 = eaPh[(size_t)(eBeg + base) * 2 + 0];
    uint4 qA1 = eaPh[(size_t)(eBeg + base) * 2 + 1];
    int curDst = sdA.y;
    float acc = 0.f;

    for (int g = 0; g < ngroups; ++g) {
        const int cur = g & 1;
        __syncthreads();                 // buf[cur] visible to all waves

        // reg-stage next group (issue loads now, LDS-write after compute)
        const bool hasNext = (g + 1) < ngroups;
        uint4 sMain = make_uint4(0, 0, 0, 0), sPad = make_uint4(0, 0, 0, 0);
        int pMain = 0, pPad = 0;
        if (hasNext) {
            const int nBeg = eBeg + (g + 1) * G;
            sMain = eaPh[(size_t)nBeg * 2 + tid];
            pMain = ((const int*)(pairsSD + nBeg))[tid];
            if (tid < 8) {
                const int w = tid >> 1, cc = tid & 1;
                const int src = min(nBeg + G + w * 32, N_EDGES - 1);
                sPad = eaPh[(size_t)src * 2 + cc];
            }
            if (tid < 16) {
                const int w = tid >> 2, sl = (tid >> 1) & 1, ic = tid & 1;
                const int src = min(nBeg + G + w * 32 + sl, N_EDGES - 1);
                pPad = ((const int*)pairsSD)[src * 2 + ic];
            }
        }

        const uint4* eaW = &eaS[cur][wid * WSLOT_EA];
        const int2*  pW  = &pairsS[cur][wid * WSLOT_P];

#pragma unroll 4
        for (int e = 0; e < 32; ++e) {
            // all prefetch indices valid thanks to pads — no clamps, no selects
            int2 sdC = pW[e + 2];
            float hsB = (float)h16[(((unsigned)sdB.x) << 6) + lane];
            uint4 qB0 = eaW[(e + 1) * 2 + 0];
            uint4 qB1 = eaW[(e + 1) * 2 + 1];
            // current edge from last iteration's registers; hsA seeds m1
            float m0 = beR, m1 = hsA;
            m0 = dot2u(qA0.x, weh[0], m0); m0 = dot2u(qA0.y, weh[1], m0);
            m0 = dot2u(qA0.z, weh[2], m0); m0 = dot2u(qA0.w, weh[3], m0);
            m1 = dot2u(qA1.x, weh[4], m1); m1 = dot2u(qA1.y, weh[5], m1);
            m1 = dot2u(qA1.z, weh[6], m1); m1 = dot2u(qA1.w, weh[7], m1);
            float m = m0 + m1;
            if (sdA.y != curDst) {                   // wave-uniform branch
                atomicAdd(&aggr[(((unsigned)curDst) << 6) + lane], acc);
                acc = 0.f;
                curDst = sdA.y;
            }
            acc += fmaxf(m, 0.f);                    // ReLU
            sdA = sdB; sdB = sdC; hsA = hsB;
            qA0 = qB0; qA1 = qB1;
        }

        if (hasNext) {
            const int j = tid >> 1, c = tid & 1;
            eaS[cur ^ 1][(j >> 5) * WSLOT_EA + (j & 31) * 2 + c] = sMain;
            ((int*)pairsS[cur ^ 1])[((j >> 5) * WSLOT_P + (j & 31)) * 2 + c] = pMain;
            if (tid < 8) {
                const int w = tid >> 1, cc = tid & 1;
                eaS[cur ^ 1][w * WSLOT_EA + 64 + cc] = sPad;
            }
            if (tid < 16) {
                const int w = tid >> 2, sl = (tid >> 1) & 1, ic = tid & 1;
                ((int*)pairsS[cur ^ 1])[(w * WSLOT_P + 32 + sl) * 2 + ic] = pPad;
            }
        }
    }
    atomicAdd(&aggr[(((unsigned)curDst) << 6) + lane], acc);
}

// ---------------- node kernel: t = (float)h16 + aggr; leaky(t@Wn + bn) -> fp16; zeroes aggr ----------------
template <bool LAST>
__global__ __launch_bounds__(256, 4) void node_kernel(
    const _Float16* __restrict__ h16, float* __restrict__ aggr,
    const float* __restrict__ Wn, const float* __restrict__ bn,
    const float* __restrict__ Wf, const float* __restrict__ bf,
    _Float16* __restrict__ hout16, float* __restrict__ out)
{
    __shared__ float WnS[F * F];    // 16 KB
    __shared__ float tS[NPB * F];   // 8 KB
    const int tid  = threadIdx.x;
    const int lane = tid & 63;
    const int wid  = tid >> 6;
    const int n0   = blockIdx.x * NPB;
    const int nCnt = min(NPB, N_NODES - n0);

    {   // stage Wn (coalesced float4)
        const float4* s4 = (const float4*)Wn;
        float4* d4 = (float4*)WnS;
        for (int i = tid; i < F * F / 4; i += 256) d4[i] = s4[i];
    }
    {   // stage t = (float)h16 + aggr; zero aggr for the next layer
        float4* t4 = (float4*)tS;
        const uint2* h2 = (const uint2*)(h16 + ((size_t)n0 << 6));
        float4* a4 = (float4*)(aggr + ((size_t)n0 << 6));
        const float4 z = make_float4(0.f, 0.f, 0.f, 0.f);
        for (int i = tid; i < NPB * F / 4; i += 256) {
            if ((i >> 4) < nCnt) {
                uint2 hv = h2[i];
                half2_t x0 = __builtin_bit_cast(half2_t, hv.x);
                half2_t x1 = __builtin_bit_cast(half2_t, hv.y);
                float4 av = a4[i];
                t4[i] = make_float4((float)x0[0] + av.x, (float)x0[1] + av.y,
                                    (float)x1[0] + av.z, (float)x1[1] + av.w);
                a4[i] = z;
            } else {
                t4[i] = z;
            }
        }
    }
    __syncthreads();

    // wave handles 8 nodes; Wn cols + t rows both from LDS; bounded unroll
    const int nb = wid * NPW;
    const float bnR = bn[lane];
    float accv[NPW];
#pragma unroll
    for (int i = 0; i < NPW; ++i) accv[i] = bnR;
#pragma unroll 4
    for (int q = 0; q < 16; ++q) {
        const float w0 = WnS[(4 * q + 0) * F + lane];
        const float w1 = WnS[(4 * q + 1) * F + lane];
        const float w2 = WnS[(4 * q + 2) * F + lane];
        const float w3 = WnS[(4 * q + 3) * F + lane];
#pragma unroll
        for (int i = 0; i < NPW; ++i) {
            const float4 t4 = *(const float4*)&tS[((nb + i) << 6) + (q << 2)];
            accv[i] = fmaf(t4.w, w3, fmaf(t4.z, w2, fmaf(t4.y, w1, fmaf(t4.x, w0, accv[i]))));
        }
    }
    float wf0 = 0.f, wf1 = 0.f, bf0 = 0.f, bf1 = 0.f;
    if (LAST) { wf0 = Wf[lane * 2]; wf1 = Wf[lane * 2 + 1]; bf0 = bf[0]; bf1 = bf[1]; }
#pragma unroll
    for (int i = 0; i < NPW; ++i) {
        const int nl = nb + i;
        if (nl >= nCnt) break;
        float acc = accv[i];
        acc = acc >= 0.f ? acc : NEG_SLOPE * acc;    // LeakyReLU
        if (!LAST) {
            hout16[((size_t)(n0 + nl) << 6) + lane] = (_Float16)acc;
        } else {
            float v0 = acc * wf0, v1 = acc * wf1;
#pragma unroll
            for (int off = 32; off; off >>= 1) {
                v0 += __shfl_down(v0, off);
                v1 += __shfl_down(v1, off);
            }
            if (lane == 0) {
                out[(n0 + nl) * 2 + 0] = v0 + bf0;
                out[(n0 + nl) * 2 + 1] = v1 + bf1;
            }
        }
    }
}

extern "C" void kernel_launch(void* const* d_in, const int* in_sizes, int n_in,
                              void* d_out, int out_size, void* d_ws, size_t ws_size,
                              hipStream_t stream) {
    const float* x  = (const float*)d_in[0];
    const int*   ei = (const int*)d_in[1];       // int32 per harness contract
    const float* ea = (const float*)d_in[2];
    const float* Wn = (const float*)d_in[3];
    const float* bn = (const float*)d_in[4];
    const float* We = (const float*)d_in[5];     // [3,16,64]
    const float* be = (const float*)d_in[6];     // [3,64]
    const float* W1 = (const float*)d_in[7];
    const float* b1 = (const float*)d_in[8];
    const float* W2 = (const float*)d_in[9];
    const float* b2 = (const float*)d_in[10];
    float* out = (float*)d_out;

    size_t off = 0;
    char* base = (char*)d_ws;
    auto alloc = [&](size_t bytes) {
        off = (off + 255) & ~(size_t)255;
        char* p = base + off;
        off += bytes;
        return p;
    };
    int*   count    = (int*)alloc(sizeof(int) * N_NODES * CPAD);   // line-padded
    int*   rowptr   = (int*)alloc(sizeof(int) * (N_NODES + 1));
    int*   rank     = (int*)alloc(sizeof(int) * N_EDGES);
    int*   blockSum = (int*)alloc(sizeof(int) * SCAN_NB);
    int2*  pairsSD  = (int2*)alloc(sizeof(int2) * N_EDGES);
    int*   eid      = (int*)alloc(sizeof(int) * N_EDGES);
    uint4* eaPh     = (uint4*)alloc(32ull * N_EDGES);   // fp16 ea, CSR order
    float* aggr     = (float*)alloc(sizeof(float) * (size_t)N_NODES * F);
    _Float16* x16   = (_Float16*)alloc(2ull * N_NODES * F);
    _Float16* hA16  = (_Float16*)alloc(2ull * N_NODES * F);
    _Float16* hB16  = (_Float16*)alloc(2ull * N_NODES * F);
    float* Wf       = (float*)alloc(sizeof(float) * F * 2);
    float* bf       = (float*)alloc(sizeof(float) * 2);

    fuse_weights_kernel<<<1, 128, 0, stream>>>(W1, b1, W2, b2, Wf, bf);

    // aggr zeroed once here; node kernels restore it to zero every layer
    hipMemsetAsync(aggr, 0, sizeof(float) * (size_t)N_NODES * F, stream);

    // x -> fp16 once
    tofp16_kernel<<<(N_NODES * F / 4 + 255) / 256, 256, 0, stream>>>(
        (const float4*)x, (uint2*)x16);

    // CSR build: one atomic pass (hist stores per-edge rank); placement is
    // atomic-free with the scan block-offset folded in; ea permuted once.
    hipMemsetAsync(count, 0, sizeof(int) * N_NODES * CPAD, stream);
    hist_kernel<<<(N_EDGES + 255) / 256, 256, 0, stream>>>(ei, count, rank);
    scan_partial_kernel<<<SCAN_NB, SCAN_B, 0, stream>>>(count, rowptr, blockSum);
    scan_tops_kernel<<<1, 64, 0, stream>>>(blockSum);
    place_kernel<<<(N_EDGES + 255) / 256, 256, 0, stream>>>(ei, rowptr, blockSum,
                                                            rank, pairsSD, eid);
    permute_kernel<<<(N_EDGES * 2 + 255) / 256, 256, 0, stream>>>(
        (const float4*)ea, eid, eaPh);

    const _Float16* hcur = x16;
    _Float16* houts[3] = {hA16, hB16, nullptr};
    for (int l = 0; l < 3; ++l) {
        edge_kernel<<<NBLK_E, 256, 0, stream>>>(hcur, pairsSD, eaPh,
                                                We + (size_t)l * EDIM * F,
                                                be + (size_t)l * F, aggr);
        if (l < 2) {
            node_kernel<false><<<NBLK, 256, 0, stream>>>(hcur, aggr, Wn, bn,
                                                         Wf, bf, houts[l], out);
            hcur = houts[l];
        } else {
            node_kernel<true><<<NBLK, 256, 0, stream>>>(hcur, aggr, Wn, bn,
                                                        Wf, bf, nullptr, out);
        }
    }
}

// Round 25
// 264.931 us; speedup vs baseline: 1.0151x; 1.0151x over previous
//
#include <hip/hip_runtime.h>

#define N_NODES 50000
#define N_EDGES 800000
#define F 64
#define EDIM 16
#define NEG_SLOPE 0.01f
#define EPB 256                              // edges per block (ONE group, 8 waves x 32)
#define NBLK_E (N_EDGES / EPB)               // 3125 (exact)
#define WSLOT_EA 66                          // (32+1 pad) slots * 2 uint4
#define WSLOT_P  34                          // 32 + 2 pad slots
#define NPB 32                               // nodes per block (node kernel)
#define NBLK ((N_NODES + NPB - 1) / NPB)     // 1563
#define NPW 8                                // nodes per wave (node kernel)
#define CPAD 16                              // counter stride: 1 per 64B line
#define SCAN_B 1024
#define SCAN_NB ((N_NODES + SCAN_B - 1) / SCAN_B)   // 49

typedef _Float16 half2_t __attribute__((ext_vector_type(2)));

__device__ __forceinline__ float dot2u(unsigned u, half2_t w, float acc) {
    return __builtin_amdgcn_fdot2(__builtin_bit_cast(half2_t, u), w, acc, false);
}

// ---------------- CSR build ----------------
__global__ __launch_bounds__(256) void hist_kernel(const int* __restrict__ ei,
                                                   int* __restrict__ count,
                                                   int* __restrict__ rank) {
    int e = blockIdx.x * blockDim.x + threadIdx.x;
    if (e < N_EDGES)
        rank[e] = atomicAdd(&count[ei[N_EDGES + e] * CPAD], 1);
}

__global__ __launch_bounds__(SCAN_B) void scan_partial_kernel(const int* __restrict__ count,
                                                              int* __restrict__ rowptr,
                                                              int* __restrict__ blockSum) {
    __shared__ int buf[SCAN_B];
    const int b = blockIdx.x, tid = threadIdx.x;
    const int i = b * SCAN_B + tid;
    int v = (i < N_NODES) ? count[i * CPAD] : 0;
    buf[tid] = v;
    __syncthreads();
    for (int off = 1; off < SCAN_B; off <<= 1) {
        int t = (tid >= off) ? buf[tid - off] : 0;
        __syncthreads();
        buf[tid] += t;
        __syncthreads();
    }
    if (i < N_NODES) rowptr[i] = buf[tid] - v;      // exclusive within block
    if (tid == SCAN_B - 1) blockSum[b] = buf[tid];
}

__global__ void scan_tops_kernel(int* __restrict__ blockSum) {
    const int lane = threadIdx.x;                    // 64 threads = 1 wave
    int v = (lane < SCAN_NB) ? blockSum[lane] : 0;
    int s = v;
    for (int off = 1; off < 64; off <<= 1) {
        int t = __shfl_up(s, off);
        if (lane >= off) s += t;
    }
    if (lane < SCAN_NB) blockSum[lane] = s - v;      // exclusive block offsets
}

// atomic-free placement: pos = rowptr[d] + blockSum[d/1024] + rank[e]
__global__ __launch_bounds__(256) void place_kernel(const int* __restrict__ ei,
                                                    const int* __restrict__ rowptr,
                                                    const int* __restrict__ blockSum,
                                                    const int* __restrict__ rank,
                                                    int2* __restrict__ pairsSD,
                                                    int* __restrict__ eid) {
    int e = blockIdx.x * blockDim.x + threadIdx.x;
    if (e < N_EDGES) {
        int s = ei[e];
        int d = ei[N_EDGES + e];
        int pos = rowptr[d] + blockSum[d >> 10] + rank[e];
        pairsSD[pos] = make_int2(s, d);
        eid[pos] = e;
    }
}

// gather-permute + fp32->fp16 convert: eaPh[j] = (half)ea[eid[j]].
__global__ __launch_bounds__(256) void permute_kernel(const float4* __restrict__ ea4,
                                                      const int* __restrict__ eid,
                                                      uint4* __restrict__ eaPh) {
    int t = blockIdx.x * blockDim.x + threadIdx.x;
    if (t < N_EDGES * 2) {
        int j = t >> 1, c = t & 1;
        size_t r = (size_t)eid[j];
        float4 a = ea4[(r << 2) + (c << 1)];
        float4 b = ea4[(r << 2) + (c << 1) + 1];
        half2_t h0, h1, h2, h3;
        h0[0] = (_Float16)a.x; h0[1] = (_Float16)a.y;
        h1[0] = (_Float16)a.z; h1[1] = (_Float16)a.w;
        h2[0] = (_Float16)b.x; h2[1] = (_Float16)b.y;
        h3[0] = (_Float16)b.z; h3[1] = (_Float16)b.w;
        uint4 o;
        o.x = __builtin_bit_cast(unsigned, h0);
        o.y = __builtin_bit_cast(unsigned, h1);
        o.z = __builtin_bit_cast(unsigned, h2);
        o.w = __builtin_bit_cast(unsigned, h3);
        eaPh[t] = o;
    }
}

// ---------------- fuse readout weights ----------------
__global__ void fuse_weights_kernel(
    const float* __restrict__ W1, const float* __restrict__ b1,
    const float* __restrict__ W2, const float* __restrict__ b2,
    float* __restrict__ Wf, float* __restrict__ bf) {
    const int t = threadIdx.x;     // 128 threads
    const int i = t >> 1;
    const int j = t & 1;
    float acc = 0.f;
    for (int k = 0; k < 128; ++k) acc += W1[i * 128 + k] * W2[k * 2 + j];
    Wf[i * 2 + j] = acc;
    if (i == 0) {
        float accb = b2[j];
        for (int k = 0; k < 128; ++k) accb += b1[k] * W2[k * 2 + j];
        bf[j] = accb;
    }
}

// ---------------- edge kernel: single-group, 8 waves, one barrier ----------------
// Block stages its 256 edges once (ea fp16 + pairs) and each wave computes a
// 32-edge window with the clamp-free pipelined loop. Pads are zero-filled and
// only feed dead end-of-loop prefetches (h index 0 -> valid, discarded).
__global__ __launch_bounds__(512) void edge_kernel(
    const float* __restrict__ h,
    const int2* __restrict__ pairsSD,
    const uint4* __restrict__ eaPh,      // [E][2] uint4 = 16 halfs per edge
    const float* __restrict__ We, const float* __restrict__ be,
    float* __restrict__ aggr)
{
    __shared__ uint4 eaS[8 * WSLOT_EA];      // 8448 B
    __shared__ int2  pairsS[8 * WSLOT_P];    // 2176 B
    const int tid  = threadIdx.x;
    const int lane = tid & 63;
    const int wid  = tid >> 6;           // 0..7
    const int base = wid * 32;

    const int eBeg = blockIdx.x * EPB;   // all blocks exactly EPB edges

    half2_t weh[8];
#pragma unroll
    for (int k = 0; k < 8; ++k) {
        half2_t w;
        w[0] = (_Float16)We[(2 * k + 0) * F + lane];
        w[1] = (_Float16)We[(2 * k + 1) * F + lane];
        weh[k] = w;
    }
    const float beR = be[lane];

    // ---- stage the block's 256 edges (ea: 512 uint4, pairs: 512 ints) ----
    {
        const int j = tid >> 1, c = tid & 1;
        eaS[(j >> 5) * WSLOT_EA + (j & 31) * 2 + c] =
            eaPh[(size_t)eBeg * 2 + tid];
        ((int*)pairsS)[((j >> 5) * WSLOT_P + (j & 31)) * 2 + c] =
            ((const int*)(pairsSD + eBeg))[tid];
        if (tid < 16) {   // ea pads (dead values; zero-fill for defined reads)
            const int w = tid >> 1, cc = tid & 1;
            eaS[w * WSLOT_EA + 64 + cc] = make_uint4(0, 0, 0, 0);
        }
        if (tid < 32) {   // pairs pads: index 0 (valid node) for the dead h-prefetch
            const int w = tid >> 2, sl = (tid >> 1) & 1, ic = tid & 1;
            ((int*)pairsS)[(w * WSLOT_P + 32 + sl) * 2 + ic] = 0;
        }
    }
    // prime pipeline registers from global (overlaps the staging above)
    int2 sdA = pairsSD[eBeg + base];
    int2 sdB = pairsSD[eBeg + base + 1];
    float hsA = h[(((unsigned)sdA.x) << 6) + lane];
    uint4 qA0 = eaPh[(size_t)(eBeg + base) * 2 + 0];
    uint4 qA1 = eaPh[(size_t)(eBeg + base) * 2 + 1];
    int curDst = sdA.y;
    float acc = 0.f;

    __syncthreads();                     // staged data visible

    const uint4* eaW = &eaS[wid * WSLOT_EA];
    const int2*  pW  = &pairsS[wid * WSLOT_P];

#pragma unroll 4
    for (int e = 0; e < 32; ++e) {
        // all prefetch indices valid thanks to pads — no clamps, no selects
        int2 sdC = pW[e + 2];
        float hsB = h[(((unsigned)sdB.x) << 6) + lane];
        uint4 qB0 = eaW[(e + 1) * 2 + 0];
        uint4 qB1 = eaW[(e + 1) * 2 + 1];
        // current edge from last iteration's registers; hsA seeds m1
        float m0 = beR, m1 = hsA;
        m0 = dot2u(qA0.x, weh[0], m0); m0 = dot2u(qA0.y, weh[1], m0);
        m0 = dot2u(qA0.z, weh[2], m0); m0 = dot2u(qA0.w, weh[3], m0);
        m1 = dot2u(qA1.x, weh[4], m1); m1 = dot2u(qA1.y, weh[5], m1);
        m1 = dot2u(qA1.z, weh[6], m1); m1 = dot2u(qA1.w, weh[7], m1);
        float m = m0 + m1;
        if (sdA.y != curDst) {                   // wave-uniform branch
            atomicAdd(&aggr[(((unsigned)curDst) << 6) + lane], acc);
            acc = 0.f;
            curDst = sdA.y;
        }
        acc += fmaxf(m, 0.f);                    // ReLU
        sdA = sdB; sdB = sdC; hsA = hsB;
        qA0 = qB0; qA1 = qB1;
    }
    atomicAdd(&aggr[(((unsigned)curDst) << 6) + lane], acc);
}

// ---------------- node kernel: t = h + aggr; leaky(t@Wn + bn); zeroes aggr ----------------
template <bool LAST>
__global__ __launch_bounds__(256, 4) void node_kernel(
    const float* __restrict__ h, float* __restrict__ aggr,
    const float* __restrict__ Wn, const float* __restrict__ bn,
    const float* __restrict__ Wf, const float* __restrict__ bf,
    float* __restrict__ hout, float* __restrict__ out)
{
    __shared__ float WnS[F * F];    // 16 KB
    __shared__ float tS[NPB * F];   // 8 KB
    const int tid  = threadIdx.x;
    const int lane = tid & 63;
    const int wid  = tid >> 6;
    const int n0   = blockIdx.x * NPB;
    const int nCnt = min(NPB, N_NODES - n0);

    {   // stage Wn (coalesced float4)
        const float4* s4 = (const float4*)Wn;
        float4* d4 = (float4*)WnS;
        for (int i = tid; i < F * F / 4; i += 256) d4[i] = s4[i];
    }
    {   // stage t = h + aggr; zero aggr for the next layer's accumulation
        float4* t4 = (float4*)tS;
        const float4* h4 = (const float4*)(h + ((size_t)n0 << 6));
        float4* a4 = (float4*)(aggr + ((size_t)n0 << 6));
        const float4 z = make_float4(0.f, 0.f, 0.f, 0.f);
        for (int i = tid; i < NPB * F / 4; i += 256) {
            if ((i >> 4) < nCnt) {
                float4 hv = h4[i], av = a4[i];
                t4[i] = make_float4(hv.x + av.x, hv.y + av.y, hv.z + av.z, hv.w + av.w);
                a4[i] = z;
            } else {
                t4[i] = z;
            }
        }
    }
    __syncthreads();

    // wave handles 8 nodes; Wn cols + t rows both from LDS; bounded unroll
    const int nb = wid * NPW;
    const float bnR = bn[lane];
    float accv[NPW];
#pragma unroll
    for (int i = 0; i < NPW; ++i) accv[i] = bnR;
#pragma unroll 4
    for (int q = 0; q < 16; ++q) {
        const float w0 = WnS[(4 * q + 0) * F + lane];
        const float w1 = WnS[(4 * q + 1) * F + lane];
        const float w2 = WnS[(4 * q + 2) * F + lane];
        const float w3 = WnS[(4 * q + 3) * F + lane];
#pragma unroll
        for (int i = 0; i < NPW; ++i) {
            const float4 t4 = *(const float4*)&tS[((nb + i) << 6) + (q << 2)];
            accv[i] = fmaf(t4.w, w3, fmaf(t4.z, w2, fmaf(t4.y, w1, fmaf(t4.x, w0, accv[i]))));
        }
    }
    float wf0 = 0.f, wf1 = 0.f, bf0 = 0.f, bf1 = 0.f;
    if (LAST) { wf0 = Wf[lane * 2]; wf1 = Wf[lane * 2 + 1]; bf0 = bf[0]; bf1 = bf[1]; }
#pragma unroll
    for (int i = 0; i < NPW; ++i) {
        const int nl = nb + i;
        if (nl >= nCnt) break;
        float acc = accv[i];
        acc = acc >= 0.f ? acc : NEG_SLOPE * acc;    // LeakyReLU
        if (!LAST) {
            hout[((size_t)(n0 + nl) << 6) + lane] = acc;
        } else {
            float v0 = acc * wf0, v1 = acc * wf1;
#pragma unroll
            for (int off = 32; off; off >>= 1) {
                v0 += __shfl_down(v0, off);
                v1 += __shfl_down(v1, off);
            }
            if (lane == 0) {
                out[(n0 + nl) * 2 + 0] = v0 + bf0;
                out[(n0 + nl) * 2 + 1] = v1 + bf1;
            }
        }
    }
}

extern "C" void kernel_launch(void* const* d_in, const int* in_sizes, int n_in,
                              void* d_out, int out_size, void* d_ws, size_t ws_size,
                              hipStream_t stream) {
    const float* x  = (const float*)d_in[0];
    const int*   ei = (const int*)d_in[1];       // int32 per harness contract
    const float* ea = (const float*)d_in[2];
    const float* Wn = (const float*)d_in[3];
    const float* bn = (const float*)d_in[4];
    const float* We = (const float*)d_in[5];     // [3,16,64]
    const float* be = (const float*)d_in[6];     // [3,64]
    const float* W1 = (const float*)d_in[7];
    const float* b1 = (const float*)d_in[8];
    const float* W2 = (const float*)d_in[9];
    const float* b2 = (const float*)d_in[10];
    float* out = (float*)d_out;

    size_t off = 0;
    char* base = (char*)d_ws;
    auto alloc = [&](size_t bytes) {
        off = (off + 255) & ~(size_t)255;
        char* p = base + off;
        off += bytes;
        return p;
    };
    int*   count    = (int*)alloc(sizeof(int) * N_NODES * CPAD);   // line-padded
    int*   rowptr   = (int*)alloc(sizeof(int) * (N_NODES + 1));
    int*   rank     = (int*)alloc(sizeof(int) * N_EDGES);
    int*   blockSum = (int*)alloc(sizeof(int) * SCAN_NB);
    int2*  pairsSD  = (int2*)alloc(sizeof(int2) * N_EDGES);
    int*   eid      = (int*)alloc(sizeof(int) * N_EDGES);
    uint4* eaPh     = (uint4*)alloc(32ull * N_EDGES);   // fp16 ea, CSR order
    float* aggr     = (float*)alloc(sizeof(float) * (size_t)N_NODES * F);
    float* hA       = (float*)alloc(sizeof(float) * (size_t)N_NODES * F);
    float* hB       = (float*)alloc(sizeof(float) * (size_t)N_NODES * F);
    float* Wf       = (float*)alloc(sizeof(float) * F * 2);
    float* bf       = (float*)alloc(sizeof(float) * 2);

    fuse_weights_kernel<<<1, 128, 0, stream>>>(W1, b1, W2, b2, Wf, bf);

    // aggr zeroed once here; node kernels restore it to zero every layer
    hipMemsetAsync(aggr, 0, sizeof(float) * (size_t)N_NODES * F, stream);

    // CSR build: one atomic pass (hist stores per-edge rank); placement is
    // atomic-free with the scan block-offset folded in; ea permuted once.
    hipMemsetAsync(count, 0, sizeof(int) * N_NODES * CPAD, stream);
    hist_kernel<<<(N_EDGES + 255) / 256, 256, 0, stream>>>(ei, count, rank);
    scan_partial_kernel<<<SCAN_NB, SCAN_B, 0, stream>>>(count, rowptr, blockSum);
    scan_tops_kernel<<<1, 64, 0, stream>>>(blockSum);
    place_kernel<<<(N_EDGES + 255) / 256, 256, 0, stream>>>(ei, rowptr, blockSum,
                                                            rank, pairsSD, eid);
    permute_kernel<<<(N_EDGES * 2 + 255) / 256, 256, 0, stream>>>(
        (const float4*)ea, eid, eaPh);

    const float* hcur = x;
    float* houts[3] = {hA, hB, nullptr};
    for (int l = 0; l < 3; ++l) {
        edge_kernel<<<NBLK_E, 512, 0, stream>>>(hcur, pairsSD, eaPh,
                                                We + (size_t)l * EDIM * F,
                                                be + (size_t)l * F, aggr);
        if (l < 2) {
            node_kernel<false><<<NBLK, 256, 0, stream>>>(hcur, aggr, Wn, bn,
                                                         Wf, bf, houts[l], out);
            hcur = houts[l];
        } else {
            node_kernel<true><<<NBLK, 256, 0, stream>>>(hcur, aggr, Wn, bn,
                                                        Wf, bf, nullptr, out);
        }
    }
}

// Round 26
// 259.799 us; speedup vs baseline: 1.0352x; 1.0198x over previous
//
#include <hip/hip_runtime.h>

#define N_NODES 50000
#define N_EDGES 800000
#define F 64
#define EDIM 16
#define NEG_SLOPE 0.01f
#define EPB 256                              // edges per block (ONE group, 8 waves x 32)
#define NBLK_E (N_EDGES / EPB)               // 3125 (exact)
#define WSLOT_EA 66                          // (32+1 pad) slots * 2 uint4
#define WSLOT_P  35                          // 32 + 3 pad slots (pairs depth-3)
#define NPB 32                               // nodes per block (node kernel)
#define NBLK ((N_NODES + NPB - 1) / NPB)     // 1563
#define NPW 8                                // nodes per wave (node kernel)
#define CPAD 16                              // counter stride: 1 per 64B line
#define SCAN_B 1024
#define SCAN_NB ((N_NODES + SCAN_B - 1) / SCAN_B)   // 49

typedef _Float16 half2_t __attribute__((ext_vector_type(2)));

__device__ __forceinline__ float dot2u(unsigned u, half2_t w, float acc) {
    return __builtin_amdgcn_fdot2(__builtin_bit_cast(half2_t, u), w, acc, false);
}

// ---------------- CSR build ----------------
__global__ __launch_bounds__(256) void hist_kernel(const int* __restrict__ ei,
                                                   int* __restrict__ count,
                                                   int* __restrict__ rank) {
    int e = blockIdx.x * blockDim.x + threadIdx.x;
    if (e < N_EDGES)
        rank[e] = atomicAdd(&count[ei[N_EDGES + e] * CPAD], 1);
}

__global__ __launch_bounds__(SCAN_B) void scan_partial_kernel(const int* __restrict__ count,
                                                              int* __restrict__ rowptr,
                                                              int* __restrict__ blockSum) {
    __shared__ int buf[SCAN_B];
    const int b = blockIdx.x, tid = threadIdx.x;
    const int i = b * SCAN_B + tid;
    int v = (i < N_NODES) ? count[i * CPAD] : 0;
    buf[tid] = v;
    __syncthreads();
    for (int off = 1; off < SCAN_B; off <<= 1) {
        int t = (tid >= off) ? buf[tid - off] : 0;
        __syncthreads();
        buf[tid] += t;
        __syncthreads();
    }
    if (i < N_NODES) rowptr[i] = buf[tid] - v;      // exclusive within block
    if (tid == SCAN_B - 1) blockSum[b] = buf[tid];
}

__global__ void scan_tops_kernel(int* __restrict__ blockSum) {
    const int lane = threadIdx.x;                    // 64 threads = 1 wave
    int v = (lane < SCAN_NB) ? blockSum[lane] : 0;
    int s = v;
    for (int off = 1; off < 64; off <<= 1) {
        int t = __shfl_up(s, off);
        if (lane >= off) s += t;
    }
    if (lane < SCAN_NB) blockSum[lane] = s - v;      // exclusive block offsets
}

// atomic-free placement: pos = rowptr[d] + blockSum[d/1024] + rank[e]
__global__ __launch_bounds__(256) void place_kernel(const int* __restrict__ ei,
                                                    const int* __restrict__ rowptr,
                                                    const int* __restrict__ blockSum,
                                                    const int* __restrict__ rank,
                                                    int2* __restrict__ pairsSD,
                                                    int* __restrict__ eid) {
    int e = blockIdx.x * blockDim.x + threadIdx.x;
    if (e < N_EDGES) {
        int s = ei[e];
        int d = ei[N_EDGES + e];
        int pos = rowptr[d] + blockSum[d >> 10] + rank[e];
        pairsSD[pos] = make_int2(s, d);
        eid[pos] = e;
    }
}

// gather-permute + fp32->fp16 convert: eaPh[j] = (half)ea[eid[j]].
__global__ __launch_bounds__(256) void permute_kernel(const float4* __restrict__ ea4,
                                                      const int* __restrict__ eid,
                                                      uint4* __restrict__ eaPh) {
    int t = blockIdx.x * blockDim.x + threadIdx.x;
    if (t < N_EDGES * 2) {
        int j = t >> 1, c = t & 1;
        size_t r = (size_t)eid[j];
        float4 a = ea4[(r << 2) + (c << 1)];
        float4 b = ea4[(r << 2) + (c << 1) + 1];
        half2_t h0, h1, h2, h3;
        h0[0] = (_Float16)a.x; h0[1] = (_Float16)a.y;
        h1[0] = (_Float16)a.z; h1[1] = (_Float16)a.w;
        h2[0] = (_Float16)b.x; h2[1] = (_Float16)b.y;
        h3[0] = (_Float16)b.z; h3[1] = (_Float16)b.w;
        uint4 o;
        o.x = __builtin_bit_cast(unsigned, h0);
        o.y = __builtin_bit_cast(unsigned, h1);
        o.z = __builtin_bit_cast(unsigned, h2);
        o.w = __builtin_bit_cast(unsigned, h3);
        eaPh[t] = o;
    }
}

// ---------------- fuse readout weights ----------------
__global__ void fuse_weights_kernel(
    const float* __restrict__ W1, const float* __restrict__ b1,
    const float* __restrict__ W2, const float* __restrict__ b2,
    float* __restrict__ Wf, float* __restrict__ bf) {
    const int t = threadIdx.x;     // 128 threads
    const int i = t >> 1;
    const int j = t & 1;
    float acc = 0.f;
    for (int k = 0; k < 128; ++k) acc += W1[i * 128 + k] * W2[k * 2 + j];
    Wf[i * 2 + j] = acc;
    if (i == 0) {
        float accb = b2[j];
        for (int k = 0; k < 128; ++k) accb += b1[k] * W2[k * 2 + j];
        bf[j] = accb;
    }
}

// ---------------- edge kernel: single-group, depth-2 h prefetch (pairs depth-3) ----------------
// Invariant preserved: every address used to issue a load has been in a
// register for >=1 full iteration. h now has ~2 iterations of latency cover.
__global__ __launch_bounds__(512) void edge_kernel(
    const float* __restrict__ h,
    const int2* __restrict__ pairsSD,
    const uint4* __restrict__ eaPh,      // [E][2] uint4 = 16 halfs per edge
    const float* __restrict__ We, const float* __restrict__ be,
    float* __restrict__ aggr)
{
    __shared__ uint4 eaS[8 * WSLOT_EA];      // 8448 B
    __shared__ int2  pairsS[8 * WSLOT_P];    // 2240 B
    const int tid  = threadIdx.x;
    const int lane = tid & 63;
    const int wid  = tid >> 6;           // 0..7
    const int base = wid * 32;

    const int eBeg = blockIdx.x * EPB;   // all blocks exactly EPB edges

    half2_t weh[8];
#pragma unroll
    for (int k = 0; k < 8; ++k) {
        half2_t w;
        w[0] = (_Float16)We[(2 * k + 0) * F + lane];
        w[1] = (_Float16)We[(2 * k + 1) * F + lane];
        weh[k] = w;
    }
    const float beR = be[lane];

    // ---- stage the block's 256 edges (ea: 512 uint4, pairs: 512 ints) ----
    {
        const int j = tid >> 1, c = tid & 1;
        eaS[(j >> 5) * WSLOT_EA + (j & 31) * 2 + c] =
            eaPh[(size_t)eBeg * 2 + tid];
        ((int*)pairsS)[((j >> 5) * WSLOT_P + (j & 31)) * 2 + c] =
            ((const int*)(pairsSD + eBeg))[tid];
        if (tid < 16) {   // ea pads (dead values; zero-fill for defined reads)
            const int w = tid >> 1, cc = tid & 1;
            eaS[w * WSLOT_EA + 64 + cc] = make_uint4(0, 0, 0, 0);
        }
        if (tid < 48) {   // pairs pads: 3 slots/wave; node 0 for the dead h-prefetch
            const int w = tid / 6, r = tid % 6, sl = r >> 1, ic = r & 1;
            ((int*)pairsS)[(w * WSLOT_P + 32 + sl) * 2 + ic] = 0;
        }
    }
    // prime pipeline registers from global (overlaps the staging above)
    int2 sdA = pairsSD[eBeg + base];
    int2 sdB = pairsSD[eBeg + base + 1];
    int2 sdC = pairsSD[eBeg + base + 2];
    float hsA = h[(((unsigned)sdA.x) << 6) + lane];
    float hsB = h[(((unsigned)sdB.x) << 6) + lane];
    uint4 qA0 = eaPh[(size_t)(eBeg + base) * 2 + 0];
    uint4 qA1 = eaPh[(size_t)(eBeg + base) * 2 + 1];
    int curDst = sdA.y;
    float acc = 0.f;

    __syncthreads();                     // staged data visible

    const uint4* eaW = &eaS[wid * WSLOT_EA];
    const int2*  pW  = &pairsS[wid * WSLOT_P];

#pragma unroll 4
    for (int e = 0; e < 32; ++e) {
        // pairs 3 ahead; h 2 ahead (sdC was read one iteration ago); ea 1 ahead
        int2 sdD = pW[e + 3];
        float hsC = h[(((unsigned)sdC.x) << 6) + lane];
        uint4 qB0 = eaW[(e + 1) * 2 + 0];
        uint4 qB1 = eaW[(e + 1) * 2 + 1];
        // current edge from registers >=1 iteration old; hsA seeds m1
        float m0 = beR, m1 = hsA;
        m0 = dot2u(qA0.x, weh[0], m0); m0 = dot2u(qA0.y, weh[1], m0);
        m0 = dot2u(qA0.z, weh[2], m0); m0 = dot2u(qA0.w, weh[3], m0);
        m1 = dot2u(qA1.x, weh[4], m1); m1 = dot2u(qA1.y, weh[5], m1);
        m1 = dot2u(qA1.z, weh[6], m1); m1 = dot2u(qA1.w, weh[7], m1);
        float m = m0 + m1;
        if (sdA.y != curDst) {                   // wave-uniform branch
            atomicAdd(&aggr[(((unsigned)curDst) << 6) + lane], acc);
            acc = 0.f;
            curDst = sdA.y;
        }
        acc += fmaxf(m, 0.f);                    // ReLU
        sdA = sdB; sdB = sdC; sdC = sdD;
        hsA = hsB; hsB = hsC;
        qA0 = qB0; qA1 = qB1;
    }
    atomicAdd(&aggr[(((unsigned)curDst) << 6) + lane], acc);
}

// ---------------- node kernel: t = h + aggr; leaky(t@Wn + bn); zeroes aggr ----------------
template <bool LAST>
__global__ __launch_bounds__(256, 4) void node_kernel(
    const float* __restrict__ h, float* __restrict__ aggr,
    const float* __restrict__ Wn, const float* __restrict__ bn,
    const float* __restrict__ Wf, const float* __restrict__ bf,
    float* __restrict__ hout, float* __restrict__ out)
{
    __shared__ float WnS[F * F];    // 16 KB
    __shared__ float tS[NPB * F];   // 8 KB
    const int tid  = threadIdx.x;
    const int lane = tid & 63;
    const int wid  = tid >> 6;
    const int n0   = blockIdx.x * NPB;
    const int nCnt = min(NPB, N_NODES - n0);

    {   // stage Wn (coalesced float4)
        const float4* s4 = (const float4*)Wn;
        float4* d4 = (float4*)WnS;
        for (int i = tid; i < F * F / 4; i += 256) d4[i] = s4[i];
    }
    {   // stage t = h + aggr; zero aggr for the next layer's accumulation
        float4* t4 = (float4*)tS;
        const float4* h4 = (const float4*)(h + ((size_t)n0 << 6));
        float4* a4 = (float4*)(aggr + ((size_t)n0 << 6));
        const float4 z = make_float4(0.f, 0.f, 0.f, 0.f);
        for (int i = tid; i < NPB * F / 4; i += 256) {
            if ((i >> 4) < nCnt) {
                float4 hv = h4[i], av = a4[i];
                t4[i] = make_float4(hv.x + av.x, hv.y + av.y, hv.z + av.z, hv.w + av.w);
                a4[i] = z;
            } else {
                t4[i] = z;
            }
        }
    }
    __syncthreads();

    // wave handles 8 nodes; Wn cols + t rows both from LDS; bounded unroll
    const int nb = wid * NPW;
    const float bnR = bn[lane];
    float accv[NPW];
#pragma unroll
    for (int i = 0; i < NPW; ++i) accv[i] = bnR;
#pragma unroll 4
    for (int q = 0; q < 16; ++q) {
        const float w0 = WnS[(4 * q + 0) * F + lane];
        const float w1 = WnS[(4 * q + 1) * F + lane];
        const float w2 = WnS[(4 * q + 2) * F + lane];
        const float w3 = WnS[(4 * q + 3) * F + lane];
#pragma unroll
        for (int i = 0; i < NPW; ++i) {
            const float4 t4 = *(const float4*)&tS[((nb + i) << 6) + (q << 2)];
            accv[i] = fmaf(t4.w, w3, fmaf(t4.z, w2, fmaf(t4.y, w1, fmaf(t4.x, w0, accv[i]))));
        }
    }
    float wf0 = 0.f, wf1 = 0.f, bf0 = 0.f, bf1 = 0.f;
    if (LAST) { wf0 = Wf[lane * 2]; wf1 = Wf[lane * 2 + 1]; bf0 = bf[0]; bf1 = bf[1]; }
#pragma unroll
    for (int i = 0; i < NPW; ++i) {
        const int nl = nb + i;
        if (nl >= nCnt) break;
        float acc = accv[i];
        acc = acc >= 0.f ? acc : NEG_SLOPE * acc;    // LeakyReLU
        if (!LAST) {
            hout[((size_t)(n0 + nl) << 6) + lane] = acc;
        } else {
            float v0 = acc * wf0, v1 = acc * wf1;
#pragma unroll
            for (int off = 32; off; off >>= 1) {
                v0 += __shfl_down(v0, off);
                v1 += __shfl_down(v1, off);
            }
            if (lane == 0) {
                out[(n0 + nl) * 2 + 0] = v0 + bf0;
                out[(n0 + nl) * 2 + 1] = v1 + bf1;
            }
        }
    }
}

extern "C" void kernel_launch(void* const* d_in, const int* in_sizes, int n_in,
                              void* d_out, int out_size, void* d_ws, size_t ws_size,
                              hipStream_t stream) {
    const float* x  = (const float*)d_in[0];
    const int*   ei = (const int*)d_in[1];       // int32 per harness contract
    const float* ea = (const float*)d_in[2];
    const float* Wn = (const float*)d_in[3];
    const float* bn = (const float*)d_in[4];
    const float* We = (const float*)d_in[5];     // [3,16,64]
    const float* be = (const float*)d_in[6];     // [3,64]
    const float* W1 = (const float*)d_in[7];
    const float* b1 = (const float*)d_in[8];
    const float* W2 = (const float*)d_in[9];
    const float* b2 = (const float*)d_in[10];
    float* out = (float*)d_out;

    size_t off = 0;
    char* base = (char*)d_ws;
    auto alloc = [&](size_t bytes) {
        off = (off + 255) & ~(size_t)255;
        char* p = base + off;
        off += bytes;
        return p;
    };
    int*   count    = (int*)alloc(sizeof(int) * N_NODES * CPAD);   // line-padded
    int*   rowptr   = (int*)alloc(sizeof(int) * (N_NODES + 1));
    int*   rank     = (int*)alloc(sizeof(int) * N_EDGES);
    int*   blockSum = (int*)alloc(sizeof(int) * SCAN_NB);
    int2*  pairsSD  = (int2*)alloc(sizeof(int2) * N_EDGES);
    int*   eid      = (int*)alloc(sizeof(int) * N_EDGES);
    uint4* eaPh     = (uint4*)alloc(32ull * N_EDGES);   // fp16 ea, CSR order
    float* aggr     = (float*)alloc(sizeof(float) * (size_t)N_NODES * F);
    float* hA       = (float*)alloc(sizeof(float) * (size_t)N_NODES * F);
    float* hB       = (float*)alloc(sizeof(float) * (size_t)N_NODES * F);
    float* Wf       = (float*)alloc(sizeof(float) * F * 2);
    float* bf       = (float*)alloc(sizeof(float) * 2);

    fuse_weights_kernel<<<1, 128, 0, stream>>>(W1, b1, W2, b2, Wf, bf);

    // aggr zeroed once here; node kernels restore it to zero every layer
    hipMemsetAsync(aggr, 0, sizeof(float) * (size_t)N_NODES * F, stream);

    // CSR build: one atomic pass (hist stores per-edge rank); placement is
    // atomic-free with the scan block-offset folded in; ea permuted once.
    hipMemsetAsync(count, 0, sizeof(int) * N_NODES * CPAD, stream);
    hist_kernel<<<(N_EDGES + 255) / 256, 256, 0, stream>>>(ei, count, rank);
    scan_partial_kernel<<<SCAN_NB, SCAN_B, 0, stream>>>(count, rowptr, blockSum);
    scan_tops_kernel<<<1, 64, 0, stream>>>(blockSum);
    place_kernel<<<(N_EDGES + 255) / 256, 256, 0, stream>>>(ei, rowptr, blockSum,
                                                            rank, pairsSD, eid);
    permute_kernel<<<(N_EDGES * 2 + 255) / 256, 256, 0, stream>>>(
        (const float4*)ea, eid, eaPh);

    const float* hcur = x;
    float* houts[3] = {hA, hB, nullptr};
    for (int l = 0; l < 3; ++l) {
        edge_kernel<<<NBLK_E, 512, 0, stream>>>(hcur, pairsSD, eaPh,
                                                We + (size_t)l * EDIM * F,
                                                be + (size_t)l * F, aggr);
        if (l < 2) {
            node_kernel<false><<<NBLK, 256, 0, stream>>>(hcur, aggr, Wn, bn,
                                                         Wf, bf, houts[l], out);
            hcur = houts[l];
        } else {
            node_kernel<true><<<NBLK, 256, 0, stream>>>(hcur, aggr, Wn, bn,
                                                        Wf, bf, nullptr, out);
        }
    }
}